// Round 7
// baseline (148.920 us; speedup 1.0000x reference)
//
#include <hip/hip_runtime.h>
#include <stdint.h>

#define T_STEPS  1000
#define BATCH    32
#define N_NEURON 1000
#define IN_DIM   128
#define OUT_DIM  20
#define NCHUNK   32
#define CLEN     32

typedef unsigned short ushort_t;
typedef unsigned long long ull_t;
using f32x4  = __attribute__((ext_vector_type(4))) float;
using bf16x8 = __attribute__((ext_vector_type(8))) short;

// fp32 -> bf16 (RTN-even)
static __device__ __forceinline__ ushort_t f2bf(float f) {
    unsigned u = __float_as_uint(f);
    return (ushort_t)((u + 0x7FFFu + ((u >> 16) & 1u)) >> 16);
}

// ws layout (bytes)
#define OFF_WB   0ull            // 1024*128 bf16 = 262144
#define OFF_D    262144ull       // 32*32*1000 f32 = 4,096,000
#define OFF_M    4358144ull      // same size
#define OFF_FLAG 8454144ull      // 32 ints
#define OFF_MAXM 8454272ull      // 32 floats (per-batch max spike-metric)
#define OFF_MAXD 8454400ull      // 32 floats (per-batch max |u_end|)
#define WS_NEED  8454528ull

// ============================================================================
// Kernel 0: convert W_in to bf16 (padded to 1024 rows, extra rows zeroed)
// and zero-init the per-batch reduction scalars. bf16 feeds only the spike
// decision; margin to threshold ~14 u-units vs bf16-GEMM error ~0.003.
// ============================================================================
#define NWP4 32768     // 1024*128/4

__global__ __launch_bounds__(256) void conv_wb_kernel(
    const float* __restrict__ W, ushort_t* __restrict__ Wb,
    float* __restrict__ maxM, float* __restrict__ maxD)
{
    int idx = blockIdx.x * 256 + threadIdx.x;
    if (blockIdx.x == 0 && threadIdx.x < BATCH) {
        maxM[threadIdx.x] = 0.f;
        maxD[threadIdx.x] = 0.f;
    }
    if (idx < NWP4) {
        ushort_t h[4];
#pragma unroll
        for (int j = 0; j < 4; ++j) {
            int widx = idx * 4 + j;
            int row  = widx >> 7;
            float f  = (row < N_NEURON) ? W[widx] : 0.f;
            h[j] = f2bf(f);
        }
        ((ushort4*)Wb)[idx] = make_ushort4(h[0], h[1], h[2], h[3]);
    }
}

// ============================================================================
// Kernel 1: FUSED bf16-MFMA GEMM + exponential chunk-scan, v2.
// Block (c,b): timesteps [32c,32c+32), batch b, 1024 padded neurons.
//  - A-frags loaded straight from global into registers + converted to bf16
//    (no LDS staging, no __syncthreads anywhere).
//  - B (Wb rows) double-buffered: next tile's 4 loads in flight during the
//    current tile's 8 MFMAs (fine-grained vmcnt waits).
//  - Transpose scratch stride 34 floats, b64 writes/reads: conflict-free
//    (per 16-lane phase, banks (2*l15+4q)%32 resp. (2n+2j)%32 all distinct).
//  - Per-lane serial scan (2 VALU/step), then chunk summary (u_end, u_max)
//    and per-batch atomicMax scalars for the silence fast-check.
// D layout (verified r3-r6): row(M)=t=quad*4+reg, col(N)=neuron=lane&15.
// ============================================================================
#define SCR_ST 34   // scratch row stride in floats (8B-aligned rows)

__global__ __launch_bounds__(256, 4) void fused_scan_kernel(
    const float* __restrict__ x, const ushort_t* __restrict__ Wb,
    const float* __restrict__ in_scale_p,
    float* __restrict__ Darr, float* __restrict__ Marr,
    float* __restrict__ maxM, float* __restrict__ maxD)
{
    const int c    = blockIdx.x;      // chunk
    const int b    = blockIdx.y;      // batch
    const int tid  = threadIdx.x;
    const int lane = tid & 63;
    const int wave = tid >> 6;
    const int quad = lane >> 4;
    const int l15  = lane & 15;

    __shared__ __align__(16) float scr[4][64 * SCR_ST];   // 34816 B
    float* myscr = scr[wave];

    const float a_v = expf(-1.0f / 20.0f);
    const float cc  = (1.0f - a_v) * in_scale_p[0];

    // ---- A-frags: global -> regs -> bf16 (per m-tile to bound registers) ----
    bf16x8 Af[2][4];
#pragma unroll
    for (int mt = 0; mt < 2; ++mt) {
        const int t = c * CLEN + mt * 16 + l15;
        const bool ok = t < T_STEPS;
        const float* xp = x + ((size_t)t * BATCH + b) * IN_DIM;
        float4 xa[4][2];
#pragma unroll
        for (int kb = 0; kb < 4; ++kb) {
            xa[kb][0] = ok ? *(const float4*)(xp + kb * 32 + quad * 8)
                           : make_float4(0.f, 0.f, 0.f, 0.f);
            xa[kb][1] = ok ? *(const float4*)(xp + kb * 32 + quad * 8 + 4)
                           : make_float4(0.f, 0.f, 0.f, 0.f);
        }
#pragma unroll
        for (int kb = 0; kb < 4; ++kb) {
            bf16x8 f;
            f[0] = (short)f2bf(xa[kb][0].x); f[1] = (short)f2bf(xa[kb][0].y);
            f[2] = (short)f2bf(xa[kb][0].z); f[3] = (short)f2bf(xa[kb][0].w);
            f[4] = (short)f2bf(xa[kb][1].x); f[5] = (short)f2bf(xa[kb][1].y);
            f[6] = (short)f2bf(xa[kb][1].z); f[7] = (short)f2bf(xa[kb][1].w);
            Af[mt][kb] = f;
        }
    }

    // ---- B pipeline + 16 tiles of 16 neurons ----
    const int nwbase = wave * 256;
    bf16x8 Bc[4], Bn[4];
#pragma unroll
    for (int kb = 0; kb < 4; ++kb) {
        Bc[kb] = *(const bf16x8*)(Wb + (size_t)(nwbase + l15) * IN_DIM +
                                  kb * 32 + quad * 8);
        Bn[kb] = Bc[kb];
    }

    float wmaxM = 0.f, wmaxD = 0.f;

#pragma unroll 1
    for (int g = 0; g < 4; ++g) {
#pragma unroll
        for (int tj = 0; tj < 4; ++tj) {
            const int idx = g * 4 + tj;
            if (idx < 15) {                 // prefetch next tile's B
                const int np = nwbase + (idx + 1) * 16;
#pragma unroll
                for (int kb = 0; kb < 4; ++kb)
                    Bn[kb] = *(const bf16x8*)(Wb + (size_t)(np + l15) * IN_DIM +
                                              kb * 32 + quad * 8);
            }
            f32x4 a0 = (f32x4){0.f, 0.f, 0.f, 0.f};
            f32x4 a1 = (f32x4){0.f, 0.f, 0.f, 0.f};
#pragma unroll
            for (int kb = 0; kb < 4; ++kb) {
                a0 = __builtin_amdgcn_mfma_f32_16x16x32_bf16(Af[0][kb], Bc[kb], a0, 0, 0, 0);
                a1 = __builtin_amdgcn_mfma_f32_16x16x32_bf16(Af[1][kb], Bc[kb], a1, 0, 0, 0);
            }
            // transpose-store: row = tj*16+l15 (neuron-local), col = t
            float* rp = myscr + (tj * 16 + l15) * SCR_ST + quad * 4;
            *(float2*)(rp +  0) = make_float2(a0[0], a0[1]);
            *(float2*)(rp +  2) = make_float2(a0[2], a0[3]);
            *(float2*)(rp + 16) = make_float2(a1[0], a1[1]);
            *(float2*)(rp + 18) = make_float2(a1[2], a1[3]);
#pragma unroll
            for (int kb = 0; kb < 4; ++kb) Bc[kb] = Bn[kb];
        }
        // wave-internal LDS write->read ordering (no barrier needed)
        asm volatile("s_waitcnt lgkmcnt(0)" ::: "memory");

        // ---- per-lane serial scan: lane owns neuron nwbase+g*64+lane ----
        float u = 0.f, mmax = -1e30f;
        const float2* rp2 = (const float2*)(myscr + lane * SCR_ST);
#pragma unroll
        for (int j = 0; j < 16; ++j) {
            float2 iv = rp2[j];
            u = fmaf(a_v, u, cc * iv.x); mmax = fmaxf(mmax, u);
            u = fmaf(a_v, u, cc * iv.y); mmax = fmaxf(mmax, u);
        }
        const int n = nwbase + g * 64 + lane;
        if (n < N_NEURON) {
            size_t o = ((size_t)b * NCHUNK + c) * N_NEURON + n;
            Darr[o] = u;
            Marr[o] = mmax;
            wmaxM = fmaxf(wmaxM, mmax);      // clamped >= 0 via init
            wmaxD = fmaxf(wmaxD, fabsf(u));
        }
        asm volatile("" ::: "memory");   // keep next group's writes after reads
    }

    // ---- per-batch scalar reduction (values >= 0 -> int-bits atomicMax) ----
#pragma unroll
    for (int off = 32; off > 0; off >>= 1) {
        wmaxM = fmaxf(wmaxM, __shfl_xor(wmaxM, off, 64));
        wmaxD = fmaxf(wmaxD, __shfl_xor(wmaxD, off, 64));
    }
    if (lane == 0) {
        atomicMax((int*)&maxM[b], __float_as_int(wmaxM));
        atomicMax((int*)&maxD[b], __float_as_int(wmaxD));
    }
}

// ============================================================================
// Kernel 2: resolve. Fast path: per-batch scalar silence check
//   maxM + maxD * A32/(1-A32) < TH  (upper bound on m_c + max(0,u_entry_c))
// -> out = b_out bitwise, skip the 8 MB summary read entirely.
// Slow path (bound exceeded): per-neuron composition with depth-4 pipeline,
// conservative trigger (no false negatives), sets flag for the exact sim.
// ============================================================================
__global__ __launch_bounds__(256) void resolve_kernel(
    const float* __restrict__ Darr, const float* __restrict__ Marr,
    const float* __restrict__ maxM, const float* __restrict__ maxD,
    const float* __restrict__ b_out, float* __restrict__ out,
    int* __restrict__ flag)
{
    const int b   = blockIdx.x;
    const int tid = threadIdx.x;

    const float A32 = expf(-(float)CLEN / 20.0f);
    const float TH  = 15.0f - 0.01f;

    const float bound = maxM[b] + fmaxf(maxD[b], 0.f) * (A32 / (1.0f - A32)) + 1e-3f;
    if (bound < TH) {                       // block-uniform branch
        if (tid < OUT_DIM) out[b * OUT_DIM + tid] = b_out[tid];
        if (tid == 0) flag[b] = 0;
        return;
    }

    const int g = (tid < 250) ? tid : 249;  // float4 neuron group (dup tail ok)
    float4 u = make_float4(0.f, 0.f, 0.f, 0.f);
    bool trig = false;

    float4 dA[4], mA[4], dB[4], mB[4];
    auto ld = [&](float4* db, float4* mb, int c0) {
#pragma unroll
        for (int s = 0; s < 4; ++s) {
            db[s] = ((const float4*)(Darr + ((size_t)b * NCHUNK + c0 + s) * N_NEURON))[g];
            mb[s] = ((const float4*)(Marr + ((size_t)b * NCHUNK + c0 + s) * N_NEURON))[g];
        }
    };
    auto step = [&](float4 d, float4 m) {
        trig = trig || (m.x + fmaxf(u.x, 0.f) >= TH) || (m.y + fmaxf(u.y, 0.f) >= TH)
                    || (m.z + fmaxf(u.z, 0.f) >= TH) || (m.w + fmaxf(u.w, 0.f) >= TH);
        u.x = fmaf(A32, u.x, d.x); u.y = fmaf(A32, u.y, d.y);
        u.z = fmaf(A32, u.z, d.z); u.w = fmaf(A32, u.w, d.w);
    };

    ld(dA, mA, 0);
#pragma unroll
    for (int c0 = 0; c0 < 24; c0 += 8) {
        ld(dB, mB, c0 + 4);
#pragma unroll
        for (int s = 0; s < 4; ++s) step(dA[s], mA[s]);
        ld(dA, mA, c0 + 8);
#pragma unroll
        for (int s = 0; s < 4; ++s) step(dB[s], mB[s]);
    }
    ld(dB, mB, 28);
#pragma unroll
    for (int s = 0; s < 4; ++s) step(dA[s], mA[s]);
#pragma unroll
    for (int s = 0; s < 4; ++s) step(dB[s], mB[s]);

    int any = __syncthreads_or(trig ? 1 : 0);
    if (any == 0) {
        if (tid < OUT_DIM) out[b * OUT_DIM + tid] = b_out[tid];
        if (tid == 0) flag[b] = 0;
    } else if (tid == 0) {
        flag[b] = 1;
    }
}

// ============================================================================
// Kernel 3: gated full sequential sim (round-1 structure, known correct).
// Runs only for batches whose flag is set (never, for this data). Also the
// standalone fallback when ws is too small (flag == nullptr -> always run).
// ============================================================================
__global__ __launch_bounds__(256) void rsnn_seq_kernel(
    const int* __restrict__ flag,
    const float* __restrict__ x,
    const float* __restrict__ W_in,
    const float* __restrict__ W_rec,
    const float* __restrict__ asc_amps,
    const float* __restrict__ k_decay,
    const float* __restrict__ W_out,
    const float* __restrict__ b_out,
    const float* __restrict__ in_scale_p,
    const float* __restrict__ out_scale_p,
    float* __restrict__ out)
{
    const int b = blockIdx.x;
    if (flag && flag[b] == 0) return;

    const int tid  = threadIdx.x;
    const int lane = tid & 63;
    const int wave = tid >> 6;
    const bool active = tid < (N_NEURON / 4);
    const int n0 = tid * 4;

    __shared__ ull_t smask[2][16];
    __shared__ float acc_sh[N_NEURON];
    __shared__ float xr[2][IN_DIM];

    const float a_v      = expf(-1.0f / 20.0f);
    const float a_syn    = expf(-1.0f / 5.0f);
    const float a_read   = expf(-1.0f / 20.0f);
    const float one_m_av = 1.0f - a_v;
    const float one_m_ar = 1.0f - a_read;
    const float VR = -60.0f, VTH = -45.0f;
    const float in_scale  = in_scale_p[0];
    const float out_scale = out_scale_p[0];

    float v[4], Ia[4], psc[4], f[4], acc[4], aasc[4], amp[4];
#pragma unroll
    for (int c = 0; c < 4; ++c) {
        v[c] = VR; Ia[c] = 0.f; psc[c] = 0.f; f[c] = 0.f; acc[c] = 0.f;
        aasc[c] = active ? expf(-k_decay[n0 + c]) : 0.f;
        amp[c]  = active ? asc_amps[n0 + c] : 0.f;
    }
    if (tid < 16) { smask[0][tid] = 0ull; smask[1][tid] = 0ull; }

    if (tid < IN_DIM / 4) {
        float4 xv = ((const float4*)(x + (size_t)b * IN_DIM))[tid];
        xr[0][tid * 4 + 0] = xv.x * in_scale; xr[0][tid * 4 + 1] = xv.y * in_scale;
        xr[0][tid * 4 + 2] = xv.z * in_scale; xr[0][tid * 4 + 3] = xv.w * in_scale;
    }
    int prev_any = 0;
    __syncthreads();

    for (int t = 0; t < T_STEPS; ++t) {
        const int cur = t & 1, nxt = cur ^ 1;
        if (t + 1 < T_STEPS && tid < IN_DIM / 4) {
            float4 xv = ((const float4*)(x + (size_t)((t + 1) * BATCH + b) * IN_DIM))[tid];
            xr[nxt][tid * 4 + 0] = xv.x * in_scale; xr[nxt][tid * 4 + 1] = xv.y * in_scale;
            xr[nxt][tid * 4 + 2] = xv.z * in_scale; xr[nxt][tid * 4 + 3] = xv.w * in_scale;
        }
        float4 Icur = make_float4(0.f, 0.f, 0.f, 0.f);
        if (active) {
            float s0 = 0.f, s1 = 0.f, s2 = 0.f, s3 = 0.f;
            const float4* w0 = (const float4*)(W_in + (size_t)(n0 + 0) * IN_DIM);
            const float4* w1 = (const float4*)(W_in + (size_t)(n0 + 1) * IN_DIM);
            const float4* w2 = (const float4*)(W_in + (size_t)(n0 + 2) * IN_DIM);
            const float4* w3 = (const float4*)(W_in + (size_t)(n0 + 3) * IN_DIM);
#pragma unroll 8
            for (int k4 = 0; k4 < IN_DIM / 4; ++k4) {
                float4 xv = *((const float4*)&xr[cur][0] + k4);
                float4 a0 = w0[k4], a1 = w1[k4], a2 = w2[k4], a3 = w3[k4];
                s0 += xv.x * a0.x + xv.y * a0.y + xv.z * a0.z + xv.w * a0.w;
                s1 += xv.x * a1.x + xv.y * a1.y + xv.z * a1.z + xv.w * a1.w;
                s2 += xv.x * a2.x + xv.y * a2.y + xv.z * a2.z + xv.w * a2.w;
                s3 += xv.x * a3.x + xv.y * a3.y + xv.z * a3.z + xv.w * a3.w;
            }
            Icur = make_float4(s0, s1, s2, s3);
        }

#pragma unroll
        for (int c = 0; c < 4; ++c) psc[c] *= a_syn;
        if (prev_any && active) {
#pragma unroll 1
            for (int w = 0; w < 16; ++w) {
                ull_t m = smask[nxt][w];
                while (m) {
                    int bit = __ffsll(m) - 1;
                    m &= m - 1;
                    int npre = ((w >> 2) << 8) + (bit << 2) + (w & 3);
                    const float4 wr = *(const float4*)(W_rec + (size_t)npre * N_NEURON + n0);
                    psc[0] += wr.x; psc[1] += wr.y; psc[2] += wr.z; psc[3] += wr.w;
                }
            }
        }

        float Iv[4] = {Icur.x, Icur.y, Icur.z, Icur.w};
        bool sp[4];
#pragma unroll
        for (int c = 0; c < 4; ++c) {
            float It = Iv[c] + psc[c] + Ia[c];
            float vn = VR + a_v * (v[c] - VR) + one_m_av * It;
            bool s = active && (vn - VTH >= 0.0f);
            float sf = s ? 1.0f : 0.0f;
            vn = vn - (vn - VR) * sf;
            v[c] = vn;
            Ia[c] = aasc[c] * Ia[c] + amp[c] * sf;
            f[c] = (t == 0) ? sf : (a_read * f[c] + one_m_ar * sf);
            if (t >= 199) acc[c] += f[c];
            sp[c] = s;
        }

#pragma unroll
        for (int c = 0; c < 4; ++c) {
            ull_t m = __ballot(sp[c]);
            if (lane == 0) smask[cur][wave * 4 + c] = m;
        }
        int myany = (sp[0] | sp[1] | sp[2] | sp[3]) ? 1 : 0;
        prev_any = __syncthreads_or(myany);
    }

    if (active) {
        acc_sh[n0 + 0] = acc[0]; acc_sh[n0 + 1] = acc[1];
        acc_sh[n0 + 2] = acc[2]; acc_sh[n0 + 3] = acc[3];
    }
    __syncthreads();

    const float inv_cnt = 1.0f / 801.0f;
#pragma unroll
    for (int oo = 0; oo < 5; ++oo) {
        int o = wave * 5 + oo;
        float p = 0.f;
        for (int n = lane; n < N_NEURON; n += 64)
            p += acc_sh[n] * W_out[(size_t)o * N_NEURON + n];
#pragma unroll
        for (int off = 32; off > 0; off >>= 1)
            p += __shfl_down(p, off, 64);
        if (lane == 0)
            out[b * OUT_DIM + o] = out_scale * (p * inv_cnt) + b_out[o];
    }
}

// ============================================================================
extern "C" void kernel_launch(void* const* d_in, const int* in_sizes, int n_in,
                              void* d_out, int out_size, void* d_ws, size_t ws_size,
                              hipStream_t stream)
{
    const float* x         = (const float*)d_in[0];
    const float* W_in      = (const float*)d_in[1];
    const float* W_rec     = (const float*)d_in[2];
    const float* asc_amps  = (const float*)d_in[3];
    const float* k_decay   = (const float*)d_in[4];
    const float* W_out     = (const float*)d_in[5];
    const float* b_out     = (const float*)d_in[6];
    const float* in_scale  = (const float*)d_in[7];
    const float* out_scale = (const float*)d_in[8];
    float* out = (float*)d_out;

    if (ws_size >= WS_NEED) {
        ushort_t* Wb   = (ushort_t*)((char*)d_ws + OFF_WB);
        float*    Darr = (float*)((char*)d_ws + OFF_D);
        float*    Marr = (float*)((char*)d_ws + OFF_M);
        int*      flag = (int*)((char*)d_ws + OFF_FLAG);
        float*    maxM = (float*)((char*)d_ws + OFF_MAXM);
        float*    maxD = (float*)((char*)d_ws + OFF_MAXD);
        conv_wb_kernel<<<NWP4 / 256, 256, 0, stream>>>(W_in, Wb, maxM, maxD);
        fused_scan_kernel<<<dim3(NCHUNK, BATCH), 256, 0, stream>>>(
            x, Wb, in_scale, Darr, Marr, maxM, maxD);
        resolve_kernel<<<BATCH, 256, 0, stream>>>(
            Darr, Marr, maxM, maxD, b_out, out, flag);
        rsnn_seq_kernel<<<BATCH, 256, 0, stream>>>(
            flag, x, W_in, W_rec, asc_amps, k_decay, W_out, b_out,
            in_scale, out_scale, out);
    } else {
        rsnn_seq_kernel<<<BATCH, 256, 0, stream>>>(
            nullptr, x, W_in, W_rec, asc_amps, k_decay, W_out, b_out,
            in_scale, out_scale, out);
    }
}